// Round 6
// baseline (113.271 us; speedup 1.0000x reference)
//
#include <hip/hip_runtime.h>

#define N_NODES 3072
#define IN_DIM 512
#define OUT_DIM 64
#define HEADS 8
#define NEG_SLOPE 0.2f
#define MAX_E 128            // Poisson(~31) edges/row; 128 is >17 sigma

typedef __attribute__((ext_vector_type(8))) short bf16x8;
typedef __attribute__((ext_vector_type(4))) float f32x4;
typedef __attribute__((ext_vector_type(4))) float nfloat4;   // clang-native for nontemporal builtin

#define XFRAG_TILES (N_NODES / 16)     // 192 row-tiles
#define KTILES (IN_DIM / 32)           // 16 k-tiles
#define XFRAG_THREADS (XFRAG_TILES * KTILES * 64)   // 196608
#define WFRAG_THREADS (HEADS * KTILES * 4 * 64)     // 32768

__device__ inline unsigned short f2bf(float f) {   // RNE float->bf16
    union { float f; unsigned u; } v; v.f = f;
    unsigned r = (v.u + 0x7FFF + ((v.u >> 16) & 1)) >> 16;
    return (unsigned short)r;
}
__device__ inline float bf_lo(unsigned u) { return __uint_as_float(u << 16); }
__device__ inline float bf_hi(unsigned u) { return __uint_as_float(u & 0xffff0000u); }

// Kernel 0: build bf16 fragment-ready copies of x and W.
// xfrag[rt][kt][lane][8]: lane l holds x[rt*16 + (l&15)][kt*32 + (l>>4)*8 + j]
// wfrag[head][kt][c][lane][8]: lane l holds W[head][kt*32+(l>>4)*8+j][c*16+(l&15)]
__global__ __launch_bounds__(256) void gat_prep(
    const float* __restrict__ x, const float* __restrict__ W,
    short* __restrict__ xfrag, short* __restrict__ wfrag) {
    int tid = blockIdx.x * 256 + threadIdx.x;
    if (tid < XFRAG_THREADS) {
        int lane = tid & 63;
        int kt = (tid >> 6) & (KTILES - 1);
        int rt = tid >> 10;
        int m = rt * 16 + (lane & 15);
        int k0 = kt * 32 + (lane >> 4) * 8;
        const float4* xp = (const float4*)(x + (size_t)m * IN_DIM + k0);
        float4 v0 = xp[0], v1 = xp[1];
        bf16x8 r;
        r[0] = (short)f2bf(v0.x); r[1] = (short)f2bf(v0.y);
        r[2] = (short)f2bf(v0.z); r[3] = (short)f2bf(v0.w);
        r[4] = (short)f2bf(v1.x); r[5] = (short)f2bf(v1.y);
        r[6] = (short)f2bf(v1.z); r[7] = (short)f2bf(v1.w);
        ((bf16x8*)xfrag)[tid] = r;
    } else {
        int t2 = tid - XFRAG_THREADS;
        if (t2 >= WFRAG_THREADS) return;
        int lane = t2 & 63;
        int c = (t2 >> 6) & 3;
        int kt = (t2 >> 8) & (KTILES - 1);
        int head = t2 >> 12;
        int n = c * 16 + (lane & 15);
        int k0 = kt * 32 + (lane >> 4) * 8;
        const float* wp = W + ((size_t)head * IN_DIM + k0) * OUT_DIM + n;
        bf16x8 r;
#pragma unroll
        for (int j = 0; j < 8; ++j) r[j] = (short)f2bf(wp[(size_t)j * OUT_DIM]);
        ((bf16x8*)wfrag)[t2] = r;
    }
}

// Kernel 1: h[head] = x @ W[head] via direct-fragment MFMA (no LDS staging,
// no barriers in main loop). Block = 4 waves = 32 rows x 64 cols, one head.
// Epilogue writes h as bf16 NODE-MAJOR: hb[n][head*64 + col] (L2-resident
// 3.1 MB buffer for the agg gather), plus fp32 f_src/f_dst via LDS tile.
__global__ __launch_bounds__(256) void gat_proj(
    const short* __restrict__ xfrag, const short* __restrict__ wfrag,
    const float* __restrict__ a_src, const float* __restrict__ a_dst,
    unsigned short* __restrict__ hb, float* __restrict__ fsrc, float* __restrict__ fdst) {
    __shared__ float hs[32][OUT_DIM + 1];

    const int t = threadIdx.x;
    const int lane = t & 63;
    const int w = t >> 6;
    const int head = blockIdx.y;
    const int m0 = blockIdx.x * 32;
    const int rt0 = blockIdx.x * 2;

    const bf16x8* xa = (const bf16x8*)xfrag + (size_t)rt0 * 16 * 64 + lane;
    const bf16x8* wb = (const bf16x8*)wfrag + ((size_t)head * KTILES * 4 + w) * 64 + lane;

    f32x4 acc0 = {0.f, 0.f, 0.f, 0.f};
    f32x4 acc1 = {0.f, 0.f, 0.f, 0.f};
#pragma unroll
    for (int kt = 0; kt < KTILES; ++kt) {
        bf16x8 a0 = xa[kt * 64];            // rows m0..m0+15
        bf16x8 a1 = xa[(16 + kt) * 64];     // rows m0+16..m0+31
        bf16x8 b  = wb[kt * 4 * 64];        // cols w*16..w*16+15
        acc0 = __builtin_amdgcn_mfma_f32_16x16x32_bf16(a0, b, acc0, 0, 0, 0);
        acc1 = __builtin_amdgcn_mfma_f32_16x16x32_bf16(a1, b, acc1, 0, 0, 0);
    }

    // D mapping: col=lane&15 (within tile), row=(lane>>4)*4+i
    const int col = w * 16 + (lane & 15);
    const int r0 = (lane >> 4) * 4;
    unsigned short* hp = hb + (size_t)m0 * (HEADS * OUT_DIM) + head * OUT_DIM + col;
#pragma unroll
    for (int i2 = 0; i2 < 4; ++i2) {
        hs[r0 + i2][col] = acc0[i2];
        hs[r0 + 16 + i2][col] = acc1[i2];
        hp[(size_t)(r0 + i2) * (HEADS * OUT_DIM)] = f2bf(acc0[i2]);
        hp[(size_t)(r0 + 16 + i2) * (HEADS * OUT_DIM)] = f2bf(acc1[i2]);
    }
    __syncthreads();

    // f-pass: threads 0..127 -> f_src, 128..255 -> f_dst (fp32 from LDS tile)
    {
        const float* av = (t < 128 ? a_src : a_dst) + head * OUT_DIM;
        const int tt = t & 127;
        const int row = tt >> 2, part = tt & 3;
        float s = 0.f;
#pragma unroll
        for (int n = 0; n < 16; ++n) s += hs[row][part * 16 + n] * av[part * 16 + n];
        s += __shfl_xor(s, 1, 64);
        s += __shfl_xor(s, 2, 64);
        if (part == 0) {
            float* dst = (t < 128 ? fsrc : fdst);
            dst[head * N_NODES + m0 + row] = s;
        }
    }
}

// Kernel 2: one block per row i. Nontemporal adj scan -> LDS edge list.
// Softmax: wave w, half-wave (lane>>5) handles head 2w+(lane>>5).
// Gather: wave-iteration covers 2 edges x 2 heads; lane = (e2, hh, d4) loads
// uint2 (4 bf16 dims); cross-half shfl reduce; coalesced float4 stores.
__global__ __launch_bounds__(256) void gat_agg(
    const float* __restrict__ adj, const unsigned short* __restrict__ hb,
    const float* __restrict__ fsrc, const float* __restrict__ fdst,
    float* __restrict__ out) {
    __shared__ int s_idx[MAX_E];
    __shared__ float s_p[HEADS][MAX_E];
    __shared__ float s_inv[HEADS];
    __shared__ int s_cnt;

    const int i = blockIdx.x;
    const int t = threadIdx.x;
    if (t == 0) s_cnt = 0;
    __syncthreads();

    const nfloat4* arow4 = (const nfloat4*)(adj + (size_t)i * N_NODES);
#pragma unroll
    for (int it = 0; it < 3; ++it) {
        const int jj = t + it * 256;            // 768 float4 = 3072 cols
        nfloat4 v = __builtin_nontemporal_load(arow4 + jj);   // don't evict hb from L2
        const int j = jj * 4;
        if (v.x > 0.f) { int s = atomicAdd(&s_cnt, 1); if (s < MAX_E) s_idx[s] = j; }
        if (v.y > 0.f) { int s = atomicAdd(&s_cnt, 1); if (s < MAX_E) s_idx[s] = j + 1; }
        if (v.z > 0.f) { int s = atomicAdd(&s_cnt, 1); if (s < MAX_E) s_idx[s] = j + 2; }
        if (v.w > 0.f) { int s = atomicAdd(&s_cnt, 1); if (s < MAX_E) s_idx[s] = j + 3; }
    }
    __syncthreads();
    const int E = min(s_cnt, MAX_E);            // self-loop -> E >= 1

    const int w = t >> 6;
    const int lane = t & 63;

    // ---- softmax: half-wave per head ----
    {
        const int half = lane >> 5;
        const int sl = lane & 31;
        const int head = 2 * w + half;
        const float fi = fsrc[head * N_NODES + i];

        float m = -1e30f;
        for (int k = sl; k < E; k += 32) {
            float e = fi + fdst[head * N_NODES + s_idx[k]];
            e = e > 0.f ? e : NEG_SLOPE * e;
            s_p[head][k] = e;
            m = fmaxf(m, e);
        }
#pragma unroll
        for (int o = 16; o; o >>= 1) m = fmaxf(m, __shfl_xor(m, o, 64));

        float sum = 0.f;
        for (int k = sl; k < E; k += 32) {
            float p = __expf(s_p[head][k] - m);
            s_p[head][k] = p;
            sum += p;
        }
#pragma unroll
        for (int o = 16; o; o >>= 1) sum += __shfl_xor(sum, o, 64);
        if (sl == 0) s_inv[head] = 1.f / sum;
    }
    // same wave wrote s_p/s_inv for heads 2w,2w+1 and consumes them below:
    // wave-synchronous, no barrier needed.

    // ---- gather: lane = (e2 = lane>>5, hh = (lane>>4)&1, d4 = lane&15) ----
    const int e2 = lane >> 5;
    const int hh = (lane >> 4) & 1;
    const int d4 = lane & 15;
    const int gh = 2 * w + hh;
    const unsigned short* hbase = hb + gh * OUT_DIM + d4 * 4;

    float a0 = 0.f, a1 = 0.f, a2 = 0.f, a3 = 0.f;
#pragma unroll 8
    for (int k = 0; k < E; k += 2) {
        const int kk = k + e2;
        const bool ok = kk < E;
        const float p = ok ? s_p[gh][kk] : 0.f;
        const int j = s_idx[ok ? kk : 0];
        const uint2 u = *(const uint2*)(hbase + (size_t)j * (HEADS * OUT_DIM));
        a0 = fmaf(p, bf_lo(u.x), a0);
        a1 = fmaf(p, bf_hi(u.x), a1);
        a2 = fmaf(p, bf_lo(u.y), a2);
        a3 = fmaf(p, bf_hi(u.y), a3);
    }
    a0 += __shfl_xor(a0, 32, 64);
    a1 += __shfl_xor(a1, 32, 64);
    a2 += __shfl_xor(a2, 32, 64);
    a3 += __shfl_xor(a3, 32, 64);

    if (e2 == 0) {
        const float inv = s_inv[gh];
        float4 r = {a0 * inv, a1 * inv, a2 * inv, a3 * inv};
        *(float4*)(out + (size_t)i * (HEADS * OUT_DIM) + gh * OUT_DIM + d4 * 4) = r;
    }
}

extern "C" void kernel_launch(void* const* d_in, const int* in_sizes, int n_in,
                              void* d_out, int out_size, void* d_ws, size_t ws_size,
                              hipStream_t stream) {
    const float* x     = (const float*)d_in[0];
    const float* adj   = (const float*)d_in[1];
    const float* W     = (const float*)d_in[2];
    const float* a_src = (const float*)d_in[3];
    const float* a_dst = (const float*)d_in[4];
    float* out = (float*)d_out;

    float* fsrc = (float*)d_ws;                               // [H,N]
    float* fdst = fsrc + HEADS * N_NODES;                     // [H,N]
    unsigned short* hb = (unsigned short*)(fdst + HEADS * N_NODES);   // [N, H*64] bf16
    short* xfrag = (short*)(hb + (size_t)N_NODES * HEADS * OUT_DIM);
    short* wfrag = xfrag + (size_t)XFRAG_TILES * KTILES * 64 * 8;

    gat_prep<<<(XFRAG_THREADS + WFRAG_THREADS) / 256, 256, 0, stream>>>(
        x, W, xfrag, wfrag);
    gat_proj<<<dim3(N_NODES / 32, HEADS), 256, 0, stream>>>(
        xfrag, wfrag, a_src, a_dst, hb, fsrc, fdst);
    gat_agg<<<N_NODES, 256, 0, stream>>>(adj, hb, fsrc, fdst, out);
}

// Round 8
// 107.578 us; speedup vs baseline: 1.0529x; 1.0529x over previous
//
#include <hip/hip_runtime.h>

#define N_NODES 3072
#define IN_DIM 512
#define OUT_DIM 64
#define HEADS 8
#define NEG_SLOPE 0.2f
#define MAX_E 128            // Poisson(~31) edges/row; 128 is >17 sigma

typedef __attribute__((ext_vector_type(8))) short bf16x8;
typedef __attribute__((ext_vector_type(4))) float f32x4;

#define XFRAG_TILES (N_NODES / 16)     // 192 row-tiles
#define KTILES (IN_DIM / 32)           // 16 k-tiles
#define XFRAG_THREADS (XFRAG_TILES * KTILES * 64)   // 196608
#define WFRAG_THREADS (HEADS * KTILES * 4 * 64)     // 32768

__device__ inline unsigned short f2bf(float f) {   // RNE float->bf16
    union { float f; unsigned u; } v; v.f = f;
    unsigned r = (v.u + 0x7FFF + ((v.u >> 16) & 1)) >> 16;
    return (unsigned short)r;
}

// Kernel 0: build bf16 fragment-ready copies of x and W.
// xfrag[rt][kt][lane][8]: lane l holds x[rt*16 + (l&15)][kt*32 + (l>>4)*8 + j]
// wfrag[head][kt][c][lane][8]: lane l holds W[head][kt*32+(l>>4)*8+j][c*16+(l&15)]
__global__ __launch_bounds__(256) void gat_prep(
    const float* __restrict__ x, const float* __restrict__ W,
    short* __restrict__ xfrag, short* __restrict__ wfrag) {
    int tid = blockIdx.x * 256 + threadIdx.x;
    if (tid < XFRAG_THREADS) {
        int lane = tid & 63;
        int kt = (tid >> 6) & (KTILES - 1);
        int rt = tid >> 10;
        int m = rt * 16 + (lane & 15);
        int k0 = kt * 32 + (lane >> 4) * 8;
        const float4* xp = (const float4*)(x + (size_t)m * IN_DIM + k0);
        float4 v0 = xp[0], v1 = xp[1];
        bf16x8 r;
        r[0] = (short)f2bf(v0.x); r[1] = (short)f2bf(v0.y);
        r[2] = (short)f2bf(v0.z); r[3] = (short)f2bf(v0.w);
        r[4] = (short)f2bf(v1.x); r[5] = (short)f2bf(v1.y);
        r[6] = (short)f2bf(v1.z); r[7] = (short)f2bf(v1.w);
        ((bf16x8*)xfrag)[tid] = r;
    } else {
        int t2 = tid - XFRAG_THREADS;
        if (t2 >= WFRAG_THREADS) return;
        int lane = t2 & 63;
        int c = (t2 >> 6) & 3;
        int kt = (t2 >> 8) & (KTILES - 1);
        int head = t2 >> 12;
        int n = c * 16 + (lane & 15);
        int k0 = kt * 32 + (lane >> 4) * 8;
        const float* wp = W + ((size_t)head * IN_DIM + k0) * OUT_DIM + n;
        bf16x8 r;
#pragma unroll
        for (int j = 0; j < 8; ++j) r[j] = (short)f2bf(wp[(size_t)j * OUT_DIM]);
        ((bf16x8*)wfrag)[t2] = r;
    }
}

// Kernel 1: h[head] = x @ W[head] via direct-fragment MFMA (no LDS staging,
// no barriers in main loop). Block = 4 waves = 32 rows x 64 cols, one head.
// Epilogue writes h as bf16 NODE-MAJOR: hb[n][head*64 + col] (L2-resident
// 3.1 MB buffer for the agg gather), plus fp32 f_src/f_dst via LDS tile.
__global__ __launch_bounds__(256) void gat_proj(
    const short* __restrict__ xfrag, const short* __restrict__ wfrag,
    const float* __restrict__ a_src, const float* __restrict__ a_dst,
    unsigned short* __restrict__ hb, float* __restrict__ fsrc, float* __restrict__ fdst) {
    __shared__ float hs[32][OUT_DIM + 1];

    const int t = threadIdx.x;
    const int lane = t & 63;
    const int w = t >> 6;
    const int head = blockIdx.y;
    const int m0 = blockIdx.x * 32;
    const int rt0 = blockIdx.x * 2;

    const bf16x8* xa = (const bf16x8*)xfrag + (size_t)rt0 * 16 * 64 + lane;
    const bf16x8* wb = (const bf16x8*)wfrag + ((size_t)head * KTILES * 4 + w) * 64 + lane;

    f32x4 acc0 = {0.f, 0.f, 0.f, 0.f};
    f32x4 acc1 = {0.f, 0.f, 0.f, 0.f};
#pragma unroll
    for (int kt = 0; kt < KTILES; ++kt) {
        bf16x8 a0 = xa[kt * 64];            // rows m0..m0+15
        bf16x8 a1 = xa[(16 + kt) * 64];     // rows m0+16..m0+31
        bf16x8 b  = wb[kt * 4 * 64];        // cols w*16..w*16+15
        acc0 = __builtin_amdgcn_mfma_f32_16x16x32_bf16(a0, b, acc0, 0, 0, 0);
        acc1 = __builtin_amdgcn_mfma_f32_16x16x32_bf16(a1, b, acc1, 0, 0, 0);
    }

    // D mapping: col=lane&15 (within tile), row=(lane>>4)*4+i
    const int col = w * 16 + (lane & 15);
    const int r0 = (lane >> 4) * 4;
    unsigned short* hp = hb + (size_t)m0 * (HEADS * OUT_DIM) + head * OUT_DIM + col;
#pragma unroll
    for (int i2 = 0; i2 < 4; ++i2) {
        hs[r0 + i2][col] = acc0[i2];
        hs[r0 + 16 + i2][col] = acc1[i2];
        hp[(size_t)(r0 + i2) * (HEADS * OUT_DIM)] = f2bf(acc0[i2]);
        hp[(size_t)(r0 + 16 + i2) * (HEADS * OUT_DIM)] = f2bf(acc1[i2]);
    }
    __syncthreads();

    // f-pass: threads 0..127 -> f_src, 128..255 -> f_dst (fp32 from LDS tile)
    {
        const float* av = (t < 128 ? a_src : a_dst) + head * OUT_DIM;
        const int tt = t & 127;
        const int row = tt >> 2, part = tt & 3;
        float s = 0.f;
#pragma unroll
        for (int n = 0; n < 16; ++n) s += hs[row][part * 16 + n] * av[part * 16 + n];
        s += __shfl_xor(s, 1, 64);
        s += __shfl_xor(s, 2, 64);
        if (part == 0) {
            float* dst = (t < 128 ? fsrc : fdst);
            dst[head * N_NODES + m0 + row] = s;
        }
    }
}

// Kernel 2: one block per row i. Compact edge list, then wave w handles heads
// {2w, 2w+1}: lanes 0..31 -> head 2w, lanes 32..63 -> head 2w+1, each lane
// owning 2 output dims. Gather = ONE coalesced 256B dword load per wave per
// edge (bf16 pairs, node-major hb), covering both heads. Half-wave softmax.
// NOTE: __syncthreads() between softmax (striped s_p writes) and gather
// (all-k s_p reads) — cross-lane LDS dependency must be fenced; relying on
// wave-synchronicity broke under recompilation in R7.
__global__ __launch_bounds__(256) void gat_agg(
    const float* __restrict__ adj, const unsigned short* __restrict__ hb,
    const float* __restrict__ fsrc, const float* __restrict__ fdst,
    float* __restrict__ out) {
    __shared__ int s_idx[MAX_E];
    __shared__ float s_p[HEADS][MAX_E];
    __shared__ int s_cnt;

    const int i = blockIdx.x;
    const int t = threadIdx.x;
    if (t == 0) s_cnt = 0;
    __syncthreads();

    const float4* arow4 = (const float4*)(adj + (size_t)i * N_NODES);
#pragma unroll
    for (int it = 0; it < 3; ++it) {
        const int jj = t + it * 256;            // 768 float4 = 3072 cols
        float4 v = arow4[jj];
        const int j = jj * 4;
        if (v.x > 0.f) { int s = atomicAdd(&s_cnt, 1); if (s < MAX_E) s_idx[s] = j; }
        if (v.y > 0.f) { int s = atomicAdd(&s_cnt, 1); if (s < MAX_E) s_idx[s] = j + 1; }
        if (v.z > 0.f) { int s = atomicAdd(&s_cnt, 1); if (s < MAX_E) s_idx[s] = j + 2; }
        if (v.w > 0.f) { int s = atomicAdd(&s_cnt, 1); if (s < MAX_E) s_idx[s] = j + 3; }
    }
    __syncthreads();
    const int E = min(s_cnt, MAX_E);            // self-loop -> E >= 1

    const int w = t >> 6;
    const int lane = t & 63;
    const int half = lane >> 5;                 // 0 or 1
    const int sl = lane & 31;                   // sub-lane within half
    const int head = 2 * w + half;

    const float fi = fsrc[head * N_NODES + i];

    // pass 1: logits + half-wave max
    float m = -1e30f;
    for (int k = sl; k < E; k += 32) {
        float e = fi + fdst[head * N_NODES + s_idx[k]];
        e = e > 0.f ? e : NEG_SLOPE * e;
        s_p[head][k] = e;
        m = fmaxf(m, e);
    }
#pragma unroll
    for (int o = 16; o; o >>= 1) m = fmaxf(m, __shfl_xor(m, o, 64));

    // pass 2: exp + half-wave sum
    float sum = 0.f;
    for (int k = sl; k < E; k += 32) {
        float p = __expf(s_p[head][k] - m);
        s_p[head][k] = p;
        sum += p;
    }
#pragma unroll
    for (int o = 16; o; o >>= 1) sum += __shfl_xor(sum, o, 64);
    const float inv = 1.f / sum;

    __syncthreads();   // fence striped s_p writes before all-k reads

    // gather-aggregate: lane owns dims {sl*2, sl*2+1} of its head.
    // One dword (bf16 pair) per lane per edge; wave covers 256B contiguous.
    const unsigned short* hbase = hb + head * OUT_DIM + sl * 2;
    float a0 = 0.f, a1 = 0.f;
#pragma unroll 8
    for (int k = 0; k < E; ++k) {
        const int j = s_idx[k];
        const float p = s_p[head][k];
        const unsigned u = *(const unsigned*)(hbase + (size_t)j * (HEADS * OUT_DIM));
        a0 = fmaf(p, __uint_as_float(u << 16), a0);
        a1 = fmaf(p, __uint_as_float(u & 0xffff0000u), a1);
    }
    float2 r = {a0 * inv, a1 * inv};
    *(float2*)(out + (size_t)i * (HEADS * OUT_DIM) + head * OUT_DIM + sl * 2) = r;
}

extern "C" void kernel_launch(void* const* d_in, const int* in_sizes, int n_in,
                              void* d_out, int out_size, void* d_ws, size_t ws_size,
                              hipStream_t stream) {
    const float* x     = (const float*)d_in[0];
    const float* adj   = (const float*)d_in[1];
    const float* W     = (const float*)d_in[2];
    const float* a_src = (const float*)d_in[3];
    const float* a_dst = (const float*)d_in[4];
    float* out = (float*)d_out;

    float* fsrc = (float*)d_ws;                               // [H,N]
    float* fdst = fsrc + HEADS * N_NODES;                     // [H,N]
    unsigned short* hb = (unsigned short*)(fdst + HEADS * N_NODES);   // [N, H*64] bf16
    short* xfrag = (short*)(hb + (size_t)N_NODES * HEADS * OUT_DIM);
    short* wfrag = xfrag + (size_t)XFRAG_TILES * KTILES * 64 * 8;

    gat_prep<<<(XFRAG_THREADS + WFRAG_THREADS) / 256, 256, 0, stream>>>(
        x, W, xfrag, wfrag);
    gat_proj<<<dim3(N_NODES / 32, HEADS), 256, 0, stream>>>(
        xfrag, wfrag, a_src, a_dst, hb, fsrc, fdst);
    gat_agg<<<N_NODES, 256, 0, stream>>>(adj, hb, fsrc, fdst, out);
}